// Round 1
// baseline (194.448 us; speedup 1.0000x reference)
//
#include <hip/hip_runtime.h>

#define B_TOTAL 8192
#define DIN 512
#define DOUT 128
#define KK 16

#define TB 32                 // b-rows per block
#define NIQ 4                 // i-quarters (split-K over D_in)
#define ISPAN (DIN / NIQ)     // 128 i per block
#define CI 4                  // i per LDS chunk
#define NCHUNK (ISPAN / CI)   // 32 chunks

// ---------------- transpose: src (128 x C) -> dst (C x 128) ----------------
__global__ void transpose128(const float* __restrict__ src, float* __restrict__ dst, int C) {
  __shared__ float tile[32][33];
  int c0 = blockIdx.x * 32;
  int r0 = blockIdx.y * 32;              // rows 0..127 in 4 tiles
  int tx = threadIdx.x, ty = threadIdx.y; // (32, 8)
#pragma unroll
  for (int j = 0; j < 32; j += 8)
    tile[ty + j][tx] = src[(size_t)(r0 + ty + j) * C + (c0 + tx)];
  __syncthreads();
#pragma unroll
  for (int j = 0; j < 32; j += 8)
    dst[(size_t)(c0 + ty + j) * 128 + (r0 + tx)] = tile[tx][ty + j];
}

// ---------------- main: LDS-staged gather ----------------
// grid: 1024 blocks = 256 b-tiles x 4 i-quarters; block: 256 threads
// thread = (og 0..31 o-quad, bl 0..7); each thread owns 4 b-rows x 4 o's.
__global__ __launch_bounds__(256) void kan_main(
    const float* __restrict__ x, const float* __restrict__ wt,
    const float* __restrict__ skt, const float* __restrict__ bias,
    float* __restrict__ out) {
  __shared__ __align__(16) float slab[CI * KK * DOUT]; // 8192 floats = 32 KiB
  __shared__ __align__(16) float sks[CI * DOUT];       // 512 floats = 2 KiB
  __shared__ __align__(16) float2 sxp[TB * CI];        // (pos, x) per pair, 1 KiB

  const int tid = threadIdx.x;
  const int og = tid & 31;   // o-quad: o = og*4 .. og*4+3
  const int bl = tid >> 5;   // 0..7
  const int bt = blockIdx.x >> 2;
  const int iq = blockIdx.x & 3;
  const int b0 = bt * TB;

  float acc[4][4] = {};

  for (int c = 0; c < NCHUNK; ++c) {
    const int ig0 = iq * ISPAN + c * CI;   // first global i of chunk
    __syncthreads();                        // protect LDS from previous consume

    // ---- stage per-pair scalars (pos, x) : 128 pairs ----
    if (tid < TB * CI) {
      const int b_loc = tid >> 2;
      const int il = tid & 3;
      float xv = x[(size_t)(b0 + b_loc) * DIN + ig0 + il];
      float t = (xv + 3.0f) * (1.0f / 6.0f);
      t = fminf(fmaxf(t, 0.0f), 1.0f);
      sxp[tid] = make_float2(t * 15.0f, xv);
    }
    // ---- stage skip rows: 512 floats ----
    if (tid < 128) {
      ((float4*)sks)[tid] = ((const float4*)(skt + (size_t)ig0 * DOUT))[tid];
    }
    // ---- stage weight slab: 4 i x 16 k x 128 o = 8192 floats, contiguous ----
    {
      const float4* wsrc = (const float4*)(wt + (size_t)ig0 * KK * DOUT);
      float4* sdst = (float4*)slab;
#pragma unroll
      for (int r = 0; r < 8; ++r)
        sdst[tid + r * 256] = wsrc[tid + r * 256];
    }
    __syncthreads();

    // ---- consume ----
#pragma unroll
    for (int il = 0; il < CI; ++il) {
      const float4 skv = *(const float4*)&sks[il * DOUT + og * 4];
#pragma unroll
      for (int s = 0; s < 4; ++s) {
        const int b_loc = bl * 4 + s;
        const float2 pv = sxp[b_loc * CI + il];
        const float p = pv.x, xv = pv.y;
        const float fi = floorf(p);
        const int i0 = (int)fi;
        const int i1 = (i0 < 15) ? i0 + 1 : 15;
        const float f = p - fi;
        const float omf = 1.0f - f;
        const float4 w0v = *(const float4*)&slab[(il * KK + i0) * DOUT + og * 4];
        const float4 w1v = *(const float4*)&slab[(il * KK + i1) * DOUT + og * 4];
        acc[s][0] += omf * w0v.x + f * w1v.x + xv * skv.x;
        acc[s][1] += omf * w0v.y + f * w1v.y + xv * skv.y;
        acc[s][2] += omf * w0v.z + f * w1v.z + xv * skv.z;
        acc[s][3] += omf * w0v.w + f * w1v.w + xv * skv.w;
      }
    }
  }

  // ---- epilogue: atomic accumulate across i-quarters ----
  const bool add_bias = (iq == 0);
#pragma unroll
  for (int s = 0; s < 4; ++s) {
    const int b = b0 + bl * 4 + s;
#pragma unroll
    for (int j = 0; j < 4; ++j) {
      float v = acc[s][j];
      if (add_bias) v += bias[og * 4 + j];
      atomicAdd(&out[(size_t)b * DOUT + og * 4 + j], v);
    }
  }
}

// ---------------- safety-net naive kernel (only if ws too small) ----------------
__global__ void kan_naive(const float* __restrict__ x, const float* __restrict__ w,
                          const float* __restrict__ skw, const float* __restrict__ bias,
                          float* __restrict__ out) {
  const int b = blockIdx.x;
  const int o = threadIdx.x;
  float acc = bias[o];
  for (int i = 0; i < DIN; ++i) {
    float xv = x[(size_t)b * DIN + i];
    float t = fminf(fmaxf((xv + 3.0f) * (1.0f / 6.0f), 0.0f), 1.0f);
    float p = t * 15.0f;
    float fi = floorf(p);
    int i0 = (int)fi;
    int i1 = (i0 < 15) ? i0 + 1 : 15;
    float f = p - fi;
    const float* wr = &w[((size_t)o * DIN + i) * KK];
    acc += (1.0f - f) * wr[i0] + f * wr[i1] + xv * skw[(size_t)o * DIN + i];
  }
  out[(size_t)b * DOUT + o] = acc;
}

extern "C" void kernel_launch(void* const* d_in, const int* in_sizes, int n_in,
                              void* d_out, int out_size, void* d_ws, size_t ws_size,
                              hipStream_t stream) {
  const float* x    = (const float*)d_in[0];
  const float* w    = (const float*)d_in[1];  // (128, 512, 16)
  const float* skw  = (const float*)d_in[2];  // (128, 512)
  const float* bias = (const float*)d_in[3];  // (128,)
  float* out = (float*)d_out;                 // (8192, 128) fp32

  const size_t wt_elems = (size_t)DIN * KK * DOUT;  // 1,048,576
  const size_t sk_elems = (size_t)DIN * DOUT;       // 65,536
  const size_t need = (wt_elems + sk_elems) * sizeof(float);

  if (ws_size < need) {
    // correct-but-slow fallback; should not trigger
    kan_naive<<<B_TOTAL, DOUT, 0, stream>>>(x, w, skw, bias, out);
    return;
  }

  float* wt  = (float*)d_ws;            // (8192, 128): wt[i*16+k][o]
  float* skt = wt + wt_elems;           // (512, 128):  skt[i][o]

  hipMemsetAsync(d_out, 0, (size_t)out_size * sizeof(float), stream);
  transpose128<<<dim3(DIN * KK / 32, 4), dim3(32, 8), 0, stream>>>(w, wt, DIN * KK);
  transpose128<<<dim3(DIN / 32, 4), dim3(32, 8), 0, stream>>>(skw, skt, DIN);
  kan_main<<<TB == 32 ? (B_TOTAL / TB) * NIQ : 0, 256, 0, stream>>>(x, wt, skt, bias, out);
}

// Round 2
// 109.365 us; speedup vs baseline: 1.7780x; 1.7780x over previous
//
#include <hip/hip_runtime.h>

typedef __attribute__((ext_vector_type(8))) short short8;
typedef __attribute__((ext_vector_type(4))) float f32x4;

#define DIN 512
#define DOUT 128
#define KK 16
#define BTOT 8192
#define KAUG (DIN * KK + DIN)        // 8704 augmented K (spline 8192 + skip 512)
#define NCHUNK_TOT (KAUG / 128)      // 68 chunks of BK=128
#define NSPL 4                       // split-K factor
#define CPB (NCHUNK_TOT / NSPL)      // 17 chunks per block
#define BM 64                        // b-rows per block
#define CHUNK_BYTES 32768            // W chunk: 128 o x 128 k x bf16
#define CBASE 32768                  // C-tile offset in LDS
#define LDS_BYTES 49152              // 32K W + 16K C

// round-to-nearest-even fp32 -> bf16
__device__ static inline unsigned short f2bf(float x) {
  unsigned u = __builtin_bit_cast(unsigned, x);
  return (unsigned short)((u + 0x7FFFu + ((u >> 16) & 1u)) >> 16);
}

// async global->LDS, 16B per lane (dst = wave-uniform base + lane*16)
__device__ static inline void llds16(const char* g, char* l) {
  __builtin_amdgcn_global_load_lds(
      (const __attribute__((address_space(1))) unsigned int*)g,
      (__attribute__((address_space(3))) unsigned int*)l, 16, 0, 0);
}

// ---------------- prep: pack W_aug into swizzled bf16 chunk image ----------------
// W''[g][o][kcs] granules of 16B (8 bf16), kcs = kc ^ (o&15);
// content: k = g*128 + kc*8 .. +8 ; k<8192 -> w[o][k] (w is (128,512,16) = (o,8192));
//          k>=8192 -> sk[o][k-8192].
__global__ __launch_bounds__(256) void build_wpp(const float* __restrict__ w,
                                                 const float* __restrict__ sk,
                                                 unsigned short* __restrict__ wpp) {
  const int gi = blockIdx.x * 256 + threadIdx.x;  // granule id < 68*2048
  const int g = gi >> 11;
  const int rem = gi & 2047;
  const int o = rem >> 4;
  const int kcs = rem & 15;
  const int kc = kcs ^ (o & 15);
  const int kglob = g * 128 + kc * 8;
  const float* src = (kglob < 8192) ? (w + (size_t)o * 8192 + kglob)
                                    : (sk + (size_t)o * 512 + (kglob - 8192));
  const float4 v0 = ((const float4*)src)[0];
  const float4 v1 = ((const float4*)src)[1];
  uint4 pk;
  pk.x = f2bf(v0.x) | ((unsigned)f2bf(v0.y) << 16);
  pk.y = f2bf(v0.z) | ((unsigned)f2bf(v0.w) << 16);
  pk.z = f2bf(v1.x) | ((unsigned)f2bf(v1.y) << 16);
  pk.w = f2bf(v1.z) | ((unsigned)f2bf(v1.w) << 16);
  ((uint4*)wpp)[gi] = pk;
}

// ---------------- main: fused C-construction + MFMA GEMM ----------------
// grid 512 = 128 b-tiles x 4 k-splits; block 256 (4 waves, wave-tile 32x64)
__global__ __launch_bounds__(256, 2) void kan_mfma(const float* __restrict__ x,
                                                   const unsigned short* __restrict__ wpp,
                                                   const float* __restrict__ bias,
                                                   float* __restrict__ out) {
  __shared__ __align__(16) char smem[LDS_BYTES];
  const int tid = threadIdx.x;
  const int bt = blockIdx.x >> 2;
  const int sp = blockIdx.x & 3;
  const int b0 = bt * BM;
  const int wid = tid >> 6, lane = tid & 63;
  const int lr = lane & 15, lq = lane >> 4;
  const int wm = wid & 1, wn = wid >> 1;

  f32x4 acc[2][4] = {};

  for (int c = 0; c < CPB; ++c) {
    const int g = sp * CPB + c;
    __syncthreads();  // protect LDS from previous chunk's readers

    // ---- stage W chunk (global_load_lds, 32 KiB) ----
    {
      const char* gsrc = ((const char*)wpp) + (size_t)g * CHUNK_BYTES + wid * 8192 + lane * 16;
      char* ldst = smem + wid * 8192;
#pragma unroll
      for (int it = 0; it < 8; ++it)
        llds16(gsrc + it * 1024, ldst + it * 1024);
    }

    // ---- build C tile (64 rows x 128 k, bf16, swizzled granules) ----
    if (g < 64) {
      const int ibase = g * 8;
#pragma unroll
      for (int hh = 0; hh < 2; ++hh) {
        const int p = tid + hh * 256;     // pair id 0..511
        const int bl = p >> 3, il = p & 7;
        const float xv = x[(size_t)(b0 + bl) * DIN + ibase + il];
        float t = fminf(fmaxf((xv + 3.0f) * (1.0f / 6.0f), 0.0f), 1.0f);
        const float pos = t * 15.0f;
        int i0 = (int)pos;
        i0 = i0 > 14 ? 14 : i0;
        const float f = pos - (float)i0;
        char* row = smem + CBASE + bl * 256;
        const int swz = bl & 15;
        char* g0 = row + (((il * 2) ^ swz) << 4);
        char* g1 = row + (((il * 2 + 1) ^ swz) << 4);
        *(uint4*)g0 = make_uint4(0, 0, 0, 0);
        *(uint4*)g1 = make_uint4(0, 0, 0, 0);
        const unsigned short h0 = f2bf(1.0f - f);
        const unsigned short h1 = f2bf(f);
        const int i1 = i0 + 1;  // i0<=14 so i1<=15, always distinct from i0
        *(unsigned short*)(((i0 & 8) ? g1 : g0) + (i0 & 7) * 2) = h0;
        *(unsigned short*)(((i1 & 8) ? g1 : g0) + (i1 & 7) * 2) = h1;
      }
    } else {
      // skip-augmented columns: C[b][kc] = bf16(x[b][ioff + kc*8 ..])
      const int ioff = (g - 64) * 128;
      const int bl = tid >> 2, q = tid & 3;
      const float* xr = x + (size_t)(b0 + bl) * DIN + ioff;
      char* row = smem + CBASE + bl * 256;
      const int swz = bl & 15;
#pragma unroll
      for (int gg = 0; gg < 4; ++gg) {
        const int kc = q * 4 + gg;
        const float4 v0 = ((const float4*)(xr + kc * 8))[0];
        const float4 v1 = ((const float4*)(xr + kc * 8))[1];
        uint4 pk;
        pk.x = f2bf(v0.x) | ((unsigned)f2bf(v0.y) << 16);
        pk.y = f2bf(v0.z) | ((unsigned)f2bf(v0.w) << 16);
        pk.z = f2bf(v1.x) | ((unsigned)f2bf(v1.y) << 16);
        pk.w = f2bf(v1.z) | ((unsigned)f2bf(v1.w) << 16);
        *(uint4*)(row + ((kc ^ swz) << 4)) = pk;
      }
    }
    __syncthreads();

    // ---- MFMA: 4 K32-steps, 8 mfma each per wave ----
#pragma unroll
    for (int ks = 0; ks < 4; ++ks) {
      const int swq = ((ks * 4 + lq) ^ lr) << 4;  // swizzled granule byte offset
      short8 af[2], bfr[4];
#pragma unroll
      for (int mt = 0; mt < 2; ++mt) {
        const int m = wm * 32 + mt * 16 + lr;
        af[mt] = *(const short8*)(smem + CBASE + m * 256 + swq);
      }
#pragma unroll
      for (int nt = 0; nt < 4; ++nt) {
        const int o = wn * 64 + nt * 16 + lr;
        bfr[nt] = *(const short8*)(smem + o * 256 + swq);
      }
#pragma unroll
      for (int mt = 0; mt < 2; ++mt)
#pragma unroll
        for (int nt = 0; nt < 4; ++nt)
          acc[mt][nt] = __builtin_amdgcn_mfma_f32_16x16x32_bf16(af[mt], bfr[nt], acc[mt][nt], 0, 0, 0);
    }
  }

  // ---- epilogue: atomic accumulate across k-splits; bias on split 0 ----
#pragma unroll
  for (int nt = 0; nt < 4; ++nt) {
    const int col = wn * 64 + nt * 16 + lr;
    const float bv = (sp == 0) ? bias[col] : 0.0f;
#pragma unroll
    for (int mt = 0; mt < 2; ++mt) {
      const int rowb = b0 + wm * 32 + mt * 16 + lq * 4;
#pragma unroll
      for (int r = 0; r < 4; ++r)
        atomicAdd(out + (size_t)(rowb + r) * DOUT + col, acc[mt][nt][r] + bv);
    }
  }
}

// ---------------- safety-net naive kernel (only if ws too small) ----------------
__global__ void kan_naive(const float* __restrict__ x, const float* __restrict__ w,
                          const float* __restrict__ skw, const float* __restrict__ bias,
                          float* __restrict__ out) {
  const int b = blockIdx.x;
  const int o = threadIdx.x;
  float acc = bias[o];
  for (int i = 0; i < DIN; ++i) {
    float xv = x[(size_t)b * DIN + i];
    float t = fminf(fmaxf((xv + 3.0f) * (1.0f / 6.0f), 0.0f), 1.0f);
    float p = t * 15.0f;
    float fi = floorf(p);
    int i0 = (int)fi;
    int i1 = (i0 < 15) ? i0 + 1 : 15;
    float f = p - fi;
    const float* wr = &w[((size_t)o * DIN + i) * KK];
    acc += (1.0f - f) * wr[i0] + f * wr[i1] + xv * skw[(size_t)o * DIN + i];
  }
  out[(size_t)b * DOUT + o] = acc;
}

extern "C" void kernel_launch(void* const* d_in, const int* in_sizes, int n_in,
                              void* d_out, int out_size, void* d_ws, size_t ws_size,
                              hipStream_t stream) {
  const float* x    = (const float*)d_in[0];
  const float* w    = (const float*)d_in[1];  // (128, 512, 16) fp32
  const float* skw  = (const float*)d_in[2];  // (128, 512) fp32
  const float* bias = (const float*)d_in[3];  // (128,) fp32
  float* out = (float*)d_out;                 // (8192, 128) fp32

  const size_t need = (size_t)NCHUNK_TOT * CHUNK_BYTES;  // 2,228,224 B
  if (ws_size < need) {
    kan_naive<<<BTOT, DOUT, 0, stream>>>(x, w, skw, bias, out);
    return;
  }

  unsigned short* wpp = (unsigned short*)d_ws;

  hipMemsetAsync(d_out, 0, (size_t)out_size * sizeof(float), stream);
  build_wpp<<<NCHUNK_TOT * 2048 / 256, 256, 0, stream>>>(w, skw, wpp);
  kan_mfma<<<(BTOT / BM) * NSPL, 256, 0, stream>>>(x, wpp, bias, out);
}